// Round 9
// baseline (56.763 us; speedup 1.0000x reference)
//
#include <hip/hip_runtime.h>
#include <hip/hip_fp16.h>
#include <hip/hip_cooperative_groups.h>
#include <cstdint>

#define NN 1536
#define DD 60
#define HH 64
// cooperative path: 256 blocks (one per CU), 6 rows each
#define RPB6 6
#define CBLK (NN / RPB6)  // 256
// fallback path (R5): 2 rows per block
#define RPB 2
#define ROW_BLOCKS (NN / RPB)  // 768

namespace cg = cooperative_groups;

__device__ __forceinline__ float sigmoidf_fast(float x) {
  return 1.f / (1.f + __expf(-x));
}

// ---------------- cooperative single-dispatch kernel ----------------
// Each block owns 6 rows. Phase 1: load adj rows, prep packed fp16 AB rows
// (LDS + global), zero LDS rowbuf, compact nonzeros via shfl-scan into LDS
// jlist. grid.sync(). Phase 2: R5's gather body (1 thread/entry), write
// rowbuf, then coalesced row writeout. adj nonzeros are exactly 1.0f.
__global__ __launch_bounds__(256) void fused6_kernel(
    const float* __restrict__ embed, const float* __restrict__ W1,
    const float* __restrict__ b1, const float* __restrict__ W2,
    const float* __restrict__ b2, const float* __restrict__ adj,
    const float* __restrict__ noise, const int* __restrict__ tmp,
    float* __restrict__ out, __half2* __restrict__ ABp) {
  __shared__ float rowbuf[RPB6 * NN];              // 36.9 KB
  __shared__ __align__(16) __half2 ABL[RPB6 * HH]; // 1.5 KB
  __shared__ float w2L[HH];                        // 256 B
  __shared__ unsigned short jlist[RPB6 * NN];      // 18.4 KB
  __shared__ int wsum[4], wbase[4], njtot;

  const int tid = threadIdx.x;
  const int lane = tid & 63, wid = tid >> 6;
  const int i0 = blockIdx.x * RPB6;

  // issue adj row loads early: 9 coalesced float4 per thread
  const float4* a4 = (const float4*)(adj + i0 * NN);
  float4 v[9];
#pragma unroll
  for (int k = 0; k < 9; ++k) v[k] = a4[tid + k * 256];

  if (tid < HH) w2L[tid] = W2[tid];

  // prep own 6 rows: ABL/ABp[i][h] = half2(A+b1, B)
  for (int t = tid; t < RPB6 * HH; t += 256) {
    int r = t >> 6, h = t & 63;
    int i = i0 + r;
    float accA = b1[h], accB = 0.f;
    const float* er = embed + i * DD;
#pragma unroll
    for (int d = 0; d < DD; ++d) {
      float e = er[d];
      accA += e * W1[d * HH + h];
      accB += e * W1[(DD + d) * HH + h];
    }
    __half2 p = __floats2half2_rn(accA, accB);
    ABL[t] = p;
    ABp[i * HH + h] = p;
  }

  // zero rowbuf
  float4* rb4 = (float4*)rowbuf;
  float4 z = make_float4(0.f, 0.f, 0.f, 0.f);
#pragma unroll
  for (int k = 0; k < 9; ++k) rb4[tid + k * 256] = z;

  // nonzero mask over 36 elems
  unsigned long long mask = 0ull;
#pragma unroll
  for (int k = 0; k < 9; ++k) {
    mask |= (v[k].x != 0.f) ? (1ull << (4 * k + 0)) : 0ull;
    mask |= (v[k].y != 0.f) ? (1ull << (4 * k + 1)) : 0ull;
    mask |= (v[k].z != 0.f) ? (1ull << (4 * k + 2)) : 0ull;
    mask |= (v[k].w != 0.f) ? (1ull << (4 * k + 3)) : 0ull;
  }

  int c = __popcll(mask);
  int incl = c;
#pragma unroll
  for (int off = 1; off < 64; off <<= 1) {
    int t = __shfl_up(incl, off, 64);
    if (lane >= off) incl += t;
  }
  if (lane == 63) wsum[wid] = incl;
  __syncthreads();
  if (tid == 0) {
    int tot = 0;
#pragma unroll
    for (int w = 0; w < 4; ++w) { wbase[w] = tot; tot += wsum[w]; }
    njtot = tot;
  }
  __syncthreads();

  int o = wbase[wid] + (incl - c);
  unsigned long long mm = mask;
  while (mm) {
    int b = __ffsll((unsigned long long)mm) - 1;
    mm &= mm - 1;
    int f = ((b >> 2) * 256 + tid) * 4 + (b & 3);
    int r = f / NN;
    int j = f - r * NN;
    jlist[o++] = (unsigned short)((r << 11) | j);
  }

  cg::this_grid().sync();  // all ABp rows + all lists ready

  // ---- phase 2: R5's measured-best gather body ----
  const int n = njtot;
  const float invb = 1.f / (float)(*tmp);
  const float bb = b2[0];
  for (int t = tid; t < n; t += 256) {
    unsigned e = jlist[t];
    int r = (int)(e >> 11);
    int j = (int)(e & 2047u);
    int i = i0 + r;
    const float4* G = (const float4*)(ABp + j * HH);  // 256B contiguous
    const float4* L = (const float4*)(ABL + r * HH);  // LDS broadcast
    float la_ij = bb, la_ji = bb;
#pragma unroll
    for (int q = 0; q < 16; ++q) {
      float4 g = G[q];
      float4 l = L[q];
      const __half2* gh = (const __half2*)&g;
      const __half2* lh = (const __half2*)&l;
#pragma unroll
      for (int s = 0; s < 4; ++s) {
        float2 gf = __half22float2(gh[s]);  // (A_j, B_j)
        float2 lf = __half22float2(lh[s]);  // (A_i, B_i)
        float w = w2L[4 * q + s];
        la_ij += fmaxf(lf.x + gf.y, 0.f) * w;
        la_ji += fmaxf(gf.x + lf.y, 0.f) * w;
      }
    }
    float u1 = noise[i * NN + j];
    float u2 = noise[j * NN + i];
    float lg1 = __logf(u1) - __logf(1.f - u1);
    float lg2 = __logf(u2) - __logf(1.f - u2);
    float g1 = sigmoidf_fast((lg1 + la_ij) * invb);
    float g2 = sigmoidf_fast((lg2 + la_ji) * invb);
    rowbuf[r * NN + j] = 0.5f * (g1 + g2);  // adj nonzero == 1.0 exactly
  }

  __syncthreads();

  float4* o4 = (float4*)(out + i0 * NN);
#pragma unroll
  for (int k = 0; k < 9; ++k) o4[tid + k * 256] = rb4[tid + k * 256];
}

// ---------------- fallback path: exact R5 kernels (19.7 us) ----------------
__global__ __launch_bounds__(256) void prep_kernel(
    const float* __restrict__ embed, const float* __restrict__ W1,
    const float* __restrict__ b1, __half2* __restrict__ ABp) {
  int t = blockIdx.x * blockDim.x + threadIdx.x;
  int i = t >> 6, h = t & 63;
  float accA = b1[h], accB = 0.f;
  const float* er = embed + i * DD;
#pragma unroll
  for (int d = 0; d < DD; ++d) {
    float e = er[d];
    accA += e * W1[d * HH + h];
    accB += e * W1[(DD + d) * HH + h];
  }
  ABp[i * HH + h] = __floats2half2_rn(accA, accB);
}

__global__ __launch_bounds__(256) void row_kernel(
    const __half2* __restrict__ ABp, const float* __restrict__ W2,
    const float* __restrict__ b2, const float* __restrict__ adj,
    const float* __restrict__ noise, const int* __restrict__ tmp,
    float* __restrict__ out) {
  __shared__ float rowbuf[RPB * NN];
  __shared__ float w2L[HH];
  __shared__ __align__(16) __half2 ABL[RPB * HH];
  __shared__ unsigned short jlist[RPB * NN];
  __shared__ int njtot;

  const int tid = threadIdx.x;
  const int lane = tid & 63;
  const int i0 = blockIdx.x * RPB;

  const float4* a4 = (const float4*)(adj + i0 * NN);
  float4 v0 = a4[tid + 0 * 256];
  float4 v1 = a4[tid + 1 * 256];
  float4 v2 = a4[tid + 2 * 256];

  if (tid < HH) w2L[tid] = W2[tid];
  if (tid >= 64 && tid < 64 + RPB * HH) {
    int x = tid - 64;
    ABL[x] = ABp[i0 * HH + x];
  }
  if (tid == 192) njtot = 0;

  float4* rb4 = (float4*)rowbuf;
  float4 z = make_float4(0.f, 0.f, 0.f, 0.f);
  rb4[tid + 0 * 256] = z;
  rb4[tid + 1 * 256] = z;
  rb4[tid + 2 * 256] = z;

  __syncthreads();

  unsigned mask = 0;
  mask |= (v0.x != 0.f) ? 0x001u : 0u;
  mask |= (v0.y != 0.f) ? 0x002u : 0u;
  mask |= (v0.z != 0.f) ? 0x004u : 0u;
  mask |= (v0.w != 0.f) ? 0x008u : 0u;
  mask |= (v1.x != 0.f) ? 0x010u : 0u;
  mask |= (v1.y != 0.f) ? 0x020u : 0u;
  mask |= (v1.z != 0.f) ? 0x040u : 0u;
  mask |= (v1.w != 0.f) ? 0x080u : 0u;
  mask |= (v2.x != 0.f) ? 0x100u : 0u;
  mask |= (v2.y != 0.f) ? 0x200u : 0u;
  mask |= (v2.z != 0.f) ? 0x400u : 0u;
  mask |= (v2.w != 0.f) ? 0x800u : 0u;

  int c = __popc(mask);
  int incl = c;
#pragma unroll
  for (int off = 1; off < 64; off <<= 1) {
    int t = __shfl_up(incl, off, 64);
    if (lane >= off) incl += t;
  }
  int wb = 0;
  if (lane == 63) wb = atomicAdd(&njtot, incl);
  wb = __shfl(wb, 63, 64);
  int o = wb + incl - c;

  unsigned mm = mask;
  while (mm) {
    int b = __ffs((int)mm) - 1;
    mm &= mm - 1;
    int f = ((b >> 2) * 256 + tid) * 4 + (b & 3);
    int r = f / NN;
    int j = f - r * NN;
    jlist[o++] = (unsigned short)((r << 11) | j);
  }

  __syncthreads();

  const int n = njtot;
  const float invb = 1.f / (float)(*tmp);
  const float bb = b2[0];
  for (int t = tid; t < n; t += 256) {
    unsigned e = jlist[t];
    int r = (int)(e >> 11);
    int j = (int)(e & 2047u);
    int i = i0 + r;
    const float4* G = (const float4*)(ABp + j * HH);
    const float4* L = (const float4*)(ABL + r * HH);
    float la_ij = bb, la_ji = bb;
#pragma unroll
    for (int q = 0; q < 16; ++q) {
      float4 g = G[q];
      float4 l = L[q];
      const __half2* gh = (const __half2*)&g;
      const __half2* lh = (const __half2*)&l;
#pragma unroll
      for (int s = 0; s < 4; ++s) {
        float2 gf = __half22float2(gh[s]);
        float2 lf = __half22float2(lh[s]);
        float w = w2L[4 * q + s];
        la_ij += fmaxf(lf.x + gf.y, 0.f) * w;
        la_ji += fmaxf(gf.x + lf.y, 0.f) * w;
      }
    }
    float u1 = noise[i * NN + j];
    float u2 = noise[j * NN + i];
    float lg1 = __logf(u1) - __logf(1.f - u1);
    float lg2 = __logf(u2) - __logf(1.f - u2);
    float g1 = sigmoidf_fast((lg1 + la_ij) * invb);
    float g2 = sigmoidf_fast((lg2 + la_ji) * invb);
    rowbuf[r * NN + j] = 0.5f * (g1 + g2);
  }

  __syncthreads();

  float4* o4 = (float4*)(out + i0 * NN);
  o4[tid + 0 * 256] = rb4[tid + 0 * 256];
  o4[tid + 1 * 256] = rb4[tid + 1 * 256];
  o4[tid + 2 * 256] = rb4[tid + 2 * 256];
}

extern "C" void kernel_launch(void* const* d_in, const int* in_sizes, int n_in,
                              void* d_out, int out_size, void* d_ws,
                              size_t ws_size, hipStream_t stream) {
  const float* embed = (const float*)d_in[0];
  const float* W1 = (const float*)d_in[1];
  const float* b1 = (const float*)d_in[2];
  const float* W2 = (const float*)d_in[3];
  const float* b2 = (const float*)d_in[4];
  const float* adj = (const float*)d_in[5];
  const float* noise = (const float*)d_in[6];
  const int* tmp = (const int*)d_in[7];
  float* out = (float*)d_out;
  __half2* ABp = (__half2*)d_ws;  // NN*HH half2 = 384 KB

  void* args[] = {(void*)&embed, (void*)&W1, (void*)&b1, (void*)&W2,
                  (void*)&b2,    (void*)&adj, (void*)&noise, (void*)&tmp,
                  (void*)&out,   (void*)&ABp};
  hipError_t err = hipLaunchCooperativeKernel(
      reinterpret_cast<const void*>(&fused6_kernel), dim3(CBLK), dim3(256),
      args, 0, stream);
  if (err != hipSuccess) {
    (void)hipGetLastError();  // clear sticky error; use fallback path
    hipLaunchKernelGGL(prep_kernel, dim3(NN * HH / 256), dim3(256), 0, stream,
                       embed, W1, b1, ABp);
    hipLaunchKernelGGL(row_kernel, dim3(ROW_BLOCKS), dim3(256), 0, stream,
                       ABp, W2, b2, adj, noise, tmp, out);
  }
}